// Round 3
// baseline (222.470 us; speedup 1.0000x reference)
//
#include <hip/hip_runtime.h>

// MXFP6 quant-dequant (straight-through forward):
//   per 32-elem block: scale = 2^floor(log2(max(|x|, 1e-8)))
//   q = clip(rne(x/scale * 15), -15, 15); out = (q/15) * scale
//
// Mapping: 1 MX block = 32 consecutive floats = 8 lanes x float4.
// Block absmax via 3x shfl_xor within aligned 8-lane groups.
// floor(log2)/exp2 done exactly by masking the fp32 exponent field.
// R2: nontemporal loads/stores (zero-reuse stream, skip L2 churn) +
//     2 float4/thread at split-grid offset for 2 loads in flight.
// R3: ext_vector_type instead of HIP_vector_type — the nontemporal
//     builtins only accept native vector types.

typedef float v4f __attribute__((ext_vector_type(4)));

__global__ __launch_bounds__(256) void mxfp6_qdq_kernel(
    const v4f* __restrict__ x, v4f* __restrict__ out, int n4half) {
  int i = blockIdx.x * blockDim.x + threadIdx.x;
  if (i >= n4half) return;

  // two independent float4s, each load fully coalesced (16B/lane);
  // n4half divisible by 8 so both halves keep MX-block lane alignment
  v4f v0 = __builtin_nontemporal_load(&x[i]);
  v4f v1 = __builtin_nontemporal_load(&x[i + n4half]);

  float a0 = fmaxf(fmaxf(fabsf(v0.x), fabsf(v0.y)),
                   fmaxf(fabsf(v0.z), fabsf(v0.w)));
  float a1 = fmaxf(fmaxf(fabsf(v1.x), fabsf(v1.y)),
                   fmaxf(fabsf(v1.z), fabsf(v1.w)));
  // absmax across the 8 lanes sharing each MX block (interleaved for ILP)
  a0 = fmaxf(a0, __shfl_xor(a0, 1));
  a1 = fmaxf(a1, __shfl_xor(a1, 1));
  a0 = fmaxf(a0, __shfl_xor(a0, 2));
  a1 = fmaxf(a1, __shfl_xor(a1, 2));
  a0 = fmaxf(a0, __shfl_xor(a0, 4));
  a1 = fmaxf(a1, __shfl_xor(a1, 4));
  a0 = fmaxf(a0, 1e-8f);
  a1 = fmaxf(a1, 1e-8f);

  // scale = 2^floor(log2(a)) == exponent field of a (a normal, >= 1e-8)
  float s0 = __uint_as_float(__float_as_uint(a0) & 0x7f800000u);
  float s1 = __uint_as_float(__float_as_uint(a1) & 0x7f800000u);
  float inv0 = 15.0f / s0, rs0 = s0 * (1.0f / 15.0f);  // exact: 15/pow2
  float inv1 = 15.0f / s1, rs1 = s1 * (1.0f / 15.0f);

  v4f o0, o1;
  o0.x = fminf(fmaxf(rintf(v0.x * inv0), -15.0f), 15.0f) * rs0;
  o0.y = fminf(fmaxf(rintf(v0.y * inv0), -15.0f), 15.0f) * rs0;
  o0.z = fminf(fmaxf(rintf(v0.z * inv0), -15.0f), 15.0f) * rs0;
  o0.w = fminf(fmaxf(rintf(v0.w * inv0), -15.0f), 15.0f) * rs0;
  o1.x = fminf(fmaxf(rintf(v1.x * inv1), -15.0f), 15.0f) * rs1;
  o1.y = fminf(fmaxf(rintf(v1.y * inv1), -15.0f), 15.0f) * rs1;
  o1.z = fminf(fmaxf(rintf(v1.z * inv1), -15.0f), 15.0f) * rs1;
  o1.w = fminf(fmaxf(rintf(v1.w * inv1), -15.0f), 15.0f) * rs1;
  __builtin_nontemporal_store(o0, &out[i]);
  __builtin_nontemporal_store(o1, &out[i + n4half]);
}

extern "C" void kernel_launch(void* const* d_in, const int* in_sizes, int n_in,
                              void* d_out, int out_size, void* d_ws, size_t ws_size,
                              hipStream_t stream) {
  const float* x = (const float*)d_in[0];
  float* out = (float*)d_out;
  int n = in_sizes[0];          // 4096*8192, divisible by 64
  int n4 = n / 4;               // float4 count
  int n4half = n4 / 2;          // each thread does one float4 from each half
  int block = 256;
  int grid = (n4half + block - 1) / block;
  mxfp6_qdq_kernel<<<grid, block, 0, stream>>>(
      (const v4f*)x, (v4f*)out, n4half);
}